// Round 1
// baseline (949.723 us; speedup 1.0000x reference)
//
#include <hip/hip_runtime.h>

// Integration_block: scaling-and-squaring integration of a stationary
// velocity field. flow = SVF * 2^-7; 7x: flow = flow + trilerp(flow, p+flow).
// Shape (1, 3, 160, 192, 224) fp32. Channels are planes: [c][d][h][w],
// c=0 -> d-displacement, c=1 -> h, c=2 -> w. Zeros padding outside volume.

#define D_ 160
#define H_ 192
#define W_ 224
static constexpr int NV = D_ * H_ * W_;   // 6,881,280 voxels
static constexpr int NT = 3 * NV;         // 20,643,840 floats per buffer

__global__ __launch_bounds__(256) void scale_k(const float* __restrict__ svf,
                                               float* __restrict__ out) {
    int i = blockIdx.x * blockDim.x + threadIdx.x;
    if (i < NT) out[i] = svf[i] * 0.0078125f;  // 1/128
}

__global__ __launch_bounds__(256) void compose_k(const float* __restrict__ in,
                                                 float* __restrict__ out) {
    int idx = blockIdx.x * blockDim.x + threadIdx.x;
    if (idx >= NV) return;

    int w = idx % W_;
    int t = idx / W_;
    int h = t % H_;
    int d = t / H_;

    float f0 = in[idx];
    float f1 = in[NV + idx];
    float f2 = in[2 * NV + idx];

    float pd = (float)d + f0;
    float ph = (float)h + f1;
    float pw = (float)w + f2;

    float d0f = floorf(pd), h0f = floorf(ph), w0f = floorf(pw);
    int d0 = (int)d0f, h0 = (int)h0f, w0 = (int)w0f;
    float fd = pd - d0f, fh = ph - h0f, fw = pw - w0f;

    float acc0 = 0.f, acc1 = 0.f, acc2 = 0.f;
#pragma unroll
    for (int dz = 0; dz < 2; ++dz) {
        int cd = d0 + dz;
        if ((unsigned)cd >= (unsigned)D_) continue;
        float wz = dz ? fd : (1.f - fd);
#pragma unroll
        for (int dy = 0; dy < 2; ++dy) {
            int ch = h0 + dy;
            if ((unsigned)ch >= (unsigned)H_) continue;
            float wzy = wz * (dy ? fh : (1.f - fh));
            int rowbase = (cd * H_ + ch) * W_;
#pragma unroll
            for (int dx = 0; dx < 2; ++dx) {
                int cw = w0 + dx;
                if ((unsigned)cw >= (unsigned)W_) continue;
                float wt = wzy * (dx ? fw : (1.f - fw));
                int j = rowbase + cw;
                acc0 += wt * in[j];
                acc1 += wt * in[NV + j];
                acc2 += wt * in[2 * NV + j];
            }
        }
    }

    out[idx]          = f0 + acc0;
    out[NV + idx]     = f1 + acc1;
    out[2 * NV + idx] = f2 + acc2;
}

extern "C" void kernel_launch(void* const* d_in, const int* in_sizes, int n_in,
                              void* d_out, int out_size, void* d_ws, size_t ws_size,
                              hipStream_t stream) {
    const float* svf = (const float*)d_in[0];
    float* outp = (float*)d_out;
    float* wsA  = (float*)d_ws;   // one flow buffer (82.6 MB) in scratch

    dim3 blk(256);
    int gridScale = (NT + 255) / 256;
    scale_k<<<gridScale, blk, 0, stream>>>(svf, wsA);

    int grid = (NV + 255) / 256;
    const float* cur = wsA;   // flow lives here before each compose
    float* nxt = outp;
    for (int it = 0; it < 7; ++it) {
        compose_k<<<grid, blk, 0, stream>>>(cur, nxt);
        const float* tmp = nxt;
        nxt = (float*)cur;
        cur = tmp;
    }
    // 7 iterations (odd) -> final flow is in d_out.
}

// Round 2
// 427.994 us; speedup vs baseline: 2.2190x; 2.2190x over previous
//
#include <hip/hip_runtime.h>

// Integration_block: scaling-and-squaring SVF integration.
// flow = SVF * 2^-7; 7x: flow = flow + trilerp(flow, p + flow), zeros padding.
// Shape (1, 3, 160, 192, 224) fp32, channels planar in input/output:
// c=0 -> d-displacement, c=1 -> h, c=2 -> w.
//
// Internal layout: xyz interleaved per voxel (12 B) so the 8-corner gather is
// 4 contiguous 24 B row-loads instead of 24 scattered dwords. scale_k converts
// planar->interleaved; the final compose converts back to planar into d_out.

#define D_ 160
#define H_ 192
#define W_ 224
static constexpr int NV = D_ * H_ * W_;   // 6,881,280 voxels
static constexpr int NT = 3 * NV;

static constexpr int ROWS = 3 * W_;        // interleaved row stride (floats)
static constexpr int PLNS = 3 * H_ * W_;   // interleaved plane stride (floats)

__global__ __launch_bounds__(256) void scale_k(const float* __restrict__ svf,
                                               float* __restrict__ out) {
    int i = blockIdx.x * blockDim.x + threadIdx.x;
    if (i >= NV) return;
    float a = svf[i]          * 0.0078125f;
    float b = svf[NV + i]     * 0.0078125f;
    float c = svf[2 * NV + i] * 0.0078125f;
    out[3 * i]     = a;
    out[3 * i + 1] = b;
    out[3 * i + 2] = c;
}

// PLANAR_OUT=0: interleaved->interleaved. PLANAR_OUT=1: interleaved->planar.
template <int PLANAR_OUT>
__global__ __launch_bounds__(256) void compose_k(const float* __restrict__ in,
                                                 float* __restrict__ out) {
    int w = blockIdx.x * 32 + threadIdx.x;        // 224 / 32 = 7
    int h = blockIdx.y * 4  + threadIdx.y;        // 192 / 4  = 48
    int d = blockIdx.z * 2  + threadIdx.z;        // 160 / 2  = 80
    int idx = (d * H_ + h) * W_ + w;

    float f0 = in[3 * idx];
    float f1 = in[3 * idx + 1];
    float f2 = in[3 * idx + 2];

    float pd = (float)d + f0;
    float ph = (float)h + f1;
    float pw = (float)w + f2;

    float d0f = floorf(pd), h0f = floorf(ph), w0f = floorf(pw);
    int d0 = (int)d0f, h0 = (int)h0f, w0 = (int)w0f;
    float fd = pd - d0f, fh = ph - h0f, fw = pw - w0f;

    float acc0, acc1, acc2;

    bool interior = ((unsigned)d0 <= (unsigned)(D_ - 2)) &
                    ((unsigned)h0 <= (unsigned)(H_ - 2)) &
                    ((unsigned)w0 <= (unsigned)(W_ - 2));

    if (interior) {
        // 4 contiguous 24B loads: both w-corners' xyz per (d,h) row.
        const float* p = in + (size_t)(d0 * H_ + h0) * ROWS / H_ * H_; // keep int math simple below
        int base = (d0 * H_ + h0) * ROWS + w0 * 3;
        const float* r00 = in + base;            // (d0,   h0  )
        const float* r01 = in + base + ROWS;     // (d0,   h0+1)
        const float* r10 = in + base + PLNS;     // (d0+1, h0  )
        const float* r11 = in + base + PLNS + ROWS;
        (void)p;

        float ww0 = 1.f - fw, ww1 = fw;
        float wh0 = 1.f - fh, wh1 = fh;
        float wd0 = 1.f - fd, wd1 = fd;

        float w00 = wd0 * wh0, w01 = wd0 * wh1, w10 = wd1 * wh0, w11 = wd1 * wh1;

        acc0 = w00 * (ww0 * r00[0] + ww1 * r00[3])
             + w01 * (ww0 * r01[0] + ww1 * r01[3])
             + w10 * (ww0 * r10[0] + ww1 * r10[3])
             + w11 * (ww0 * r11[0] + ww1 * r11[3]);
        acc1 = w00 * (ww0 * r00[1] + ww1 * r00[4])
             + w01 * (ww0 * r01[1] + ww1 * r01[4])
             + w10 * (ww0 * r10[1] + ww1 * r10[4])
             + w11 * (ww0 * r11[1] + ww1 * r11[4]);
        acc2 = w00 * (ww0 * r00[2] + ww1 * r00[5])
             + w01 * (ww0 * r01[2] + ww1 * r01[5])
             + w10 * (ww0 * r10[2] + ww1 * r10[5])
             + w11 * (ww0 * r11[2] + ww1 * r11[5]);
    } else {
        acc0 = acc1 = acc2 = 0.f;
#pragma unroll
        for (int dz = 0; dz < 2; ++dz) {
            int cd = d0 + dz;
            if ((unsigned)cd >= (unsigned)D_) continue;
            float wz = dz ? fd : (1.f - fd);
#pragma unroll
            for (int dy = 0; dy < 2; ++dy) {
                int ch = h0 + dy;
                if ((unsigned)ch >= (unsigned)H_) continue;
                float wzy = wz * (dy ? fh : (1.f - fh));
                int rowbase = (cd * H_ + ch) * W_;
#pragma unroll
                for (int dx = 0; dx < 2; ++dx) {
                    int cw = w0 + dx;
                    if ((unsigned)cw >= (unsigned)W_) continue;
                    float wt = wzy * (dx ? fw : (1.f - fw));
                    int j = (rowbase + cw) * 3;
                    acc0 += wt * in[j];
                    acc1 += wt * in[j + 1];
                    acc2 += wt * in[j + 2];
                }
            }
        }
    }

    if (PLANAR_OUT) {
        out[idx]          = f0 + acc0;
        out[NV + idx]     = f1 + acc1;
        out[2 * NV + idx] = f2 + acc2;
    } else {
        out[3 * idx]     = f0 + acc0;
        out[3 * idx + 1] = f1 + acc1;
        out[3 * idx + 2] = f2 + acc2;
    }
}

extern "C" void kernel_launch(void* const* d_in, const int* in_sizes, int n_in,
                              void* d_out, int out_size, void* d_ws, size_t ws_size,
                              hipStream_t stream) {
    const float* svf = (const float*)d_in[0];
    float* outp = (float*)d_out;   // used as raw interleaved scratch until last step
    float* wsA  = (float*)d_ws;

    scale_k<<<(NV + 255) / 256, 256, 0, stream>>>(svf, wsA);

    dim3 blk(32, 4, 2);
    dim3 grd(W_ / 32, H_ / 4, D_ / 2);   // (7, 48, 80)

    // it0: wsA->out, it1: out->wsA, ... it5: out->wsA, it6: wsA->out (planar)
    const float* cur = wsA;
    float* nxt = outp;
    for (int it = 0; it < 6; ++it) {
        compose_k<0><<<grd, blk, 0, stream>>>(cur, nxt);
        const float* tmp = nxt;
        nxt = (float*)cur;
        cur = tmp;
    }
    compose_k<1><<<grd, blk, 0, stream>>>(cur, outp);
}